// Round 2
// baseline (1808.885 us; speedup 1.0000x reference)
//
#include <hip/hip_runtime.h>
#include <hip/hip_bf16.h>

// GCN: fused pipeline, fp32 throughout.
//  k_mm1:    xw1 = emb[x_ids] @ W1            (W1 in 128 VGPRs, X tile in LDS)
//  k_agg_mm: x_l = relu(agg(xw_l)+b_l);  xw_{l+1} = x_l @ W_{l+1}   (fused)
//  k_agg_mm<FINAL>: x_3 = relu(agg(xw3)+b3)
//  k_pool:   per-graph mean pool + 2-layer MLP + sigmoid

__global__ __launch_bounds__(256) void k_zero(int* __restrict__ p, int n) {
  int i = blockIdx.x * blockDim.x + threadIdx.x;
  for (; i < n; i += gridDim.x * blockDim.x) p[i] = 0;
}

__global__ __launch_bounds__(256) void k_count(const int* __restrict__ dst, int* __restrict__ cnt, int e_count) {
  int e = blockIdx.x * blockDim.x + threadIdx.x;
  if (e < e_count) atomicAdd(&cnt[dst[e]], 1);
}

// ---- hierarchical exclusive scan over cnt[0..n) -> offsets[0..n]
__global__ __launch_bounds__(256) void k_scan1(const int* __restrict__ cnt, int n, int* __restrict__ bsum) {
  __shared__ int s[256];
  int b = blockIdx.x, t = threadIdx.x;
  int base = b * 1024;
  int sum = 0;
  #pragma unroll
  for (int i = 0; i < 4; ++i) {
    int idx = base + t + i * 256;
    if (idx < n) sum += cnt[idx];
  }
  s[t] = sum; __syncthreads();
  for (int off = 128; off > 0; off >>= 1) {
    if (t < off) s[t] += s[t + off];
    __syncthreads();
  }
  if (t == 0) bsum[b] = s[0];
}

__global__ __launch_bounds__(128) void k_scan2(int* __restrict__ bsum, int nb, int* __restrict__ total_out) {
  __shared__ int sh[128];
  int t = threadIdx.x;
  sh[t] = (t < nb) ? bsum[t] : 0;
  __syncthreads();
  for (int off = 1; off < 128; off <<= 1) {
    int x = sh[t];
    int y = (t >= off) ? sh[t - off] : 0;
    __syncthreads();
    sh[t] = x + y;
    __syncthreads();
  }
  if (t < nb) bsum[t] = (t == 0) ? 0 : sh[t - 1];
  if (t == 0) *total_out = sh[127];
}

// scan3 also emits dinv = rsqrt(deg+1)
__global__ __launch_bounds__(256) void k_scan3(const int* __restrict__ cnt, int n,
                                               const int* __restrict__ bsum_ex, int* __restrict__ offsets,
                                               float* __restrict__ dinv) {
  __shared__ int sh[256];
  int b = blockIdx.x, t = threadIdx.x;
  int base = b * 1024 + t * 4;
  int v0 = (base + 0 < n) ? cnt[base + 0] : 0;
  int v1 = (base + 1 < n) ? cnt[base + 1] : 0;
  int v2 = (base + 2 < n) ? cnt[base + 2] : 0;
  int v3 = (base + 3 < n) ? cnt[base + 3] : 0;
  if (base + 0 < n) dinv[base + 0] = rsqrtf((float)v0 + 1.0f);
  if (base + 1 < n) dinv[base + 1] = rsqrtf((float)v1 + 1.0f);
  if (base + 2 < n) dinv[base + 2] = rsqrtf((float)v2 + 1.0f);
  if (base + 3 < n) dinv[base + 3] = rsqrtf((float)v3 + 1.0f);
  sh[t] = v0 + v1 + v2 + v3;
  __syncthreads();
  for (int off = 1; off < 256; off <<= 1) {
    int x = sh[t];
    int y = (t >= off) ? sh[t - off] : 0;
    __syncthreads();
    sh[t] = x + y;
    __syncthreads();
  }
  int run = bsum_ex[b] + ((t == 0) ? 0 : sh[t - 1]);
  if (base + 0 < n) offsets[base + 0] = run; run += v0;
  if (base + 1 < n) offsets[base + 1] = run; run += v1;
  if (base + 2 < n) offsets[base + 2] = run; run += v2;
  if (base + 3 < n) offsets[base + 3] = run;
}

__global__ __launch_bounds__(256) void k_scatter(const int* __restrict__ src, const int* __restrict__ dst,
                                                 const float* __restrict__ dinv, const int* __restrict__ offsets,
                                                 int* __restrict__ cursor, int2* __restrict__ csr, int e_count) {
  int e = blockIdx.x * blockDim.x + threadIdx.x;
  if (e >= e_count) return;
  int s = src[e], d = dst[e];
  int pos = offsets[d] + atomicAdd(&cursor[d], 1);
  csr[pos] = make_int2(s, __float_as_int(dinv[s] * dinv[d]));
}

// ---- layer-1 GEMM: out[r][j] = sum_k emb[ids[r]][k] * W1[k][j]
// lane = j (out col, 64); W1 in 128 VGPRs (statically indexed, fully unrolled);
// 64-row X tile staged in LDS, consumed as broadcast ds_read_b128.
__global__ __launch_bounds__(256, 2) void k_mm1(const int* __restrict__ ids,
                                                const float* __restrict__ emb,
                                                const float* __restrict__ W1,
                                                float* __restrict__ out, int n, int ntiles) {
  __shared__ float xs[64][128];  // 32 KB
  const int tid = threadIdx.x;
  const int lane = tid & 63;
  const int w = tid >> 6;
  float wreg[128];
  #pragma unroll
  for (int k = 0; k < 128; ++k) wreg[k] = W1[k * 64 + lane];

  const int half = tid & 31;   // 0..31 within half-wave
  const int rstep = tid >> 5;  // 0..7

  for (int t = blockIdx.x; t < ntiles; t += gridDim.x) {
    const int rbase = t * 64;
    __syncthreads();
    // stage 64 rows: each quarter... 8 rows per pass x 8 passes, 512B contiguous per half-wave
    #pragma unroll
    for (int it = 0; it < 8; ++it) {
      int rr = it * 8 + rstep;
      int r = rbase + rr;
      int rid = (r < n) ? ids[r] : 0;
      float4 vv = *reinterpret_cast<const float4*>(emb + (long)rid * 128 + half * 4);
      *reinterpret_cast<float4*>(&xs[rr][half * 4]) = vv;
    }
    __syncthreads();
    // wave w computes rows w*16 .. w*16+15, 4 at a time
    #pragma unroll
    for (int g = 0; g < 4; ++g) {
      const int rr0 = w * 16 + g * 4;
      const float* xr0 = xs[rr0 + 0];
      const float* xr1 = xs[rr0 + 1];
      const float* xr2 = xs[rr0 + 2];
      const float* xr3 = xs[rr0 + 3];
      float a0 = 0.f, a1 = 0.f, a2 = 0.f, a3 = 0.f;
      #pragma unroll
      for (int k4 = 0; k4 < 32; ++k4) {
        float4 x0 = *reinterpret_cast<const float4*>(xr0 + k4 * 4);
        float4 x1 = *reinterpret_cast<const float4*>(xr1 + k4 * 4);
        float4 x2 = *reinterpret_cast<const float4*>(xr2 + k4 * 4);
        float4 x3 = *reinterpret_cast<const float4*>(xr3 + k4 * 4);
        a0 = fmaf(x0.x, wreg[k4 * 4 + 0], a0); a0 = fmaf(x0.y, wreg[k4 * 4 + 1], a0);
        a0 = fmaf(x0.z, wreg[k4 * 4 + 2], a0); a0 = fmaf(x0.w, wreg[k4 * 4 + 3], a0);
        a1 = fmaf(x1.x, wreg[k4 * 4 + 0], a1); a1 = fmaf(x1.y, wreg[k4 * 4 + 1], a1);
        a1 = fmaf(x1.z, wreg[k4 * 4 + 2], a1); a1 = fmaf(x1.w, wreg[k4 * 4 + 3], a1);
        a2 = fmaf(x2.x, wreg[k4 * 4 + 0], a2); a2 = fmaf(x2.y, wreg[k4 * 4 + 1], a2);
        a2 = fmaf(x2.z, wreg[k4 * 4 + 2], a2); a2 = fmaf(x2.w, wreg[k4 * 4 + 3], a2);
        a3 = fmaf(x3.x, wreg[k4 * 4 + 0], a3); a3 = fmaf(x3.y, wreg[k4 * 4 + 1], a3);
        a3 = fmaf(x3.z, wreg[k4 * 4 + 2], a3); a3 = fmaf(x3.w, wreg[k4 * 4 + 3], a3);
      }
      int r = rbase + rr0;
      if (r + 0 < n) out[(long)(r + 0) * 64 + lane] = a0;
      if (r + 1 < n) out[(long)(r + 1) * 64 + lane] = a1;
      if (r + 2 < n) out[(long)(r + 2) * 64 + lane] = a2;
      if (r + 3 < n) out[(long)(r + 3) * 64 + lane] = a3;
    }
  }
}

// ---- fused aggregation + next-layer GEMM.
// One wave per node (lane = feature k). h = relu(agg + b). If !FINAL,
// transpose h through a per-wave LDS slot and emit h @ Wn (lane = out col j).
template <bool FINAL>
__global__ __launch_bounds__(256) void k_agg_mm(const float* __restrict__ xw,
                                                const int2* __restrict__ csr,
                                                const int* __restrict__ offs,
                                                const float* __restrict__ dinv,
                                                const float* __restrict__ bias,
                                                const float* __restrict__ Wn,
                                                float* __restrict__ out, int n) {
  __shared__ float xs[4][64];
  const int lane = threadIdx.x & 63;
  const int w = threadIdx.x >> 6;
  float wreg[64];
  if constexpr (!FINAL) {
    #pragma unroll
    for (int k = 0; k < 64; ++k) wreg[k] = Wn[k * 64 + lane];
  }
  const float bl = bias[lane];

  for (int v = blockIdx.x * 4 + w; v < n; v += gridDim.x * 4) {
    float di = dinv[v];
    float acc = fmaf(xw[(long)v * 64 + lane], di * di, bl);
    int e = offs[v];
    const int hi = offs[v + 1];
    for (; e + 4 <= hi; e += 4) {
      int2 r0 = csr[e], r1 = csr[e + 1], r2 = csr[e + 2], r3 = csr[e + 3];
      float v0 = xw[(long)r0.x * 64 + lane];
      float v1 = xw[(long)r1.x * 64 + lane];
      float v2 = xw[(long)r2.x * 64 + lane];
      float v3 = xw[(long)r3.x * 64 + lane];
      acc = fmaf(v0, __int_as_float(r0.y), acc);
      acc = fmaf(v1, __int_as_float(r1.y), acc);
      acc = fmaf(v2, __int_as_float(r2.y), acc);
      acc = fmaf(v3, __int_as_float(r3.y), acc);
    }
    for (; e < hi; ++e) {
      int2 r = csr[e];
      acc = fmaf(xw[(long)r.x * 64 + lane], __int_as_float(r.y), acc);
    }
    float val = fmaxf(acc, 0.f);
    if constexpr (FINAL) {
      out[(long)v * 64 + lane] = val;
    } else {
      // wave-internal transpose: DS ops from one wave complete in order.
      xs[w][lane] = val;
      float o = 0.f;
      #pragma unroll
      for (int k4 = 0; k4 < 16; ++k4) {
        float4 xv = *reinterpret_cast<const float4*>(&xs[w][k4 * 4]);
        o = fmaf(xv.x, wreg[k4 * 4 + 0], o);
        o = fmaf(xv.y, wreg[k4 * 4 + 1], o);
        o = fmaf(xv.z, wreg[k4 * 4 + 2], o);
        o = fmaf(xv.w, wreg[k4 * 4 + 3], o);
      }
      out[(long)v * 64 + lane] = o;
    }
  }
}

// ---- pooling (batch sorted) + 2-layer MLP head + sigmoid, block per graph
__global__ __launch_bounds__(256) void k_pool(const float* __restrict__ x, const int* __restrict__ batch, int n,
                                              const float* __restrict__ Wf1, const float* __restrict__ bf1,
                                              const float* __restrict__ Wf2, const float* __restrict__ bf2,
                                              float* __restrict__ out) {
  int g = blockIdx.x;
  int tid = threadIdx.x, lane = tid & 63, w = tid >> 6;
  int a = 0, b = n;
  while (a < b) { int m = (a + b) >> 1; if (batch[m] < g) a = m + 1; else b = m; }
  int lo = a;
  b = n;
  while (a < b) { int m = (a + b) >> 1; if (batch[m] < g + 1) a = m + 1; else b = m; }
  int hi = a;

  float acc = 0.f;
  for (int r = lo + w; r < hi; r += 4) acc += x[(long)r * 64 + lane];
  __shared__ float red[4][64];
  __shared__ float mean[64];
  red[w][lane] = acc;
  __syncthreads();
  if (w == 0) {
    float s = red[0][lane] + red[1][lane] + red[2][lane] + red[3][lane];
    mean[lane] = s / fmaxf((float)(hi - lo), 1.0f);
  }
  __syncthreads();
  if (w == 0) {
    float h = bf1[lane];
    #pragma unroll
    for (int k = 0; k < 64; ++k) h = fmaf(mean[k], Wf1[k * 64 + lane], h);
    h = fmaxf(h, 0.f);
    float vv = h * Wf2[lane];
    for (int off = 32; off > 0; off >>= 1) vv += __shfl_down(vv, off, 64);
    if (lane == 0) out[g] = 1.0f / (1.0f + expf(-(vv + bf2[0])));
  }
}

static inline char* align256(char* p) {
  return (char*)(((uintptr_t)p + 255) & ~(uintptr_t)255);
}

extern "C" void kernel_launch(void* const* d_in, const int* in_sizes, int n_in,
                              void* d_out, int out_size, void* d_ws, size_t ws_size,
                              hipStream_t stream) {
  const int*   x_ids = (const int*)d_in[0];
  const int*   edge  = (const int*)d_in[1];
  const int*   batch = (const int*)d_in[2];
  const float* emb   = (const float*)d_in[3];
  const float* W1    = (const float*)d_in[4];
  const float* b1    = (const float*)d_in[5];
  const float* W2    = (const float*)d_in[6];
  const float* b2    = (const float*)d_in[7];
  const float* W3    = (const float*)d_in[8];
  const float* b3    = (const float*)d_in[9];
  const float* Wf1   = (const float*)d_in[10];
  const float* bf1   = (const float*)d_in[11];
  const float* Wf2   = (const float*)d_in[12];
  const float* bf2   = (const float*)d_in[13];
  float* out = (float*)d_out;

  const int N = in_sizes[0];
  const int E = in_sizes[1] / 2;
  const int G = out_size;
  const int* e_src = edge;
  const int* e_dst = edge + E;

  // workspace layout
  char* p = (char*)d_ws;
  float* bufA = (float*)p;            p = align256(p + (size_t)N * 64 * 4);
  float* bufB = (float*)p;            p = align256(p + (size_t)N * 64 * 4);
  int2*  csr  = (int2*)p;             p = align256(p + (size_t)E * 8);
  float* dinv = (float*)p;            p = align256(p + (size_t)N * 4);
  int*   cntcur = (int*)p;            p = align256(p + (size_t)2 * N * 4);
  int*   offs = (int*)p;              p = align256(p + (size_t)(N + 1) * 4);
  int*   bsum = (int*)p;              p = align256(p + (size_t)1024 * 4);
  int*   cnt = cntcur;
  int*   cur = cntcur + N;
  (void)ws_size; (void)n_in;

  const int nb_scan = (N + 1023) / 1024;  // 98 for N=100000 (<=128)
  const int ntiles = (N + 63) / 64;
  dim3 blk(256);

  // CSR build (6 launches)
  k_zero<<<dim3(256), blk, 0, stream>>>(cntcur, 2 * N);
  k_count<<<dim3((E + 255) / 256), blk, 0, stream>>>(e_dst, cnt, E);
  k_scan1<<<dim3(nb_scan), blk, 0, stream>>>(cnt, N, bsum);
  k_scan2<<<dim3(1), dim3(128), 0, stream>>>(bsum, nb_scan, offs + N);
  k_scan3<<<dim3(nb_scan), blk, 0, stream>>>(cnt, N, bsum, offs, dinv);
  k_scatter<<<dim3((E + 255) / 256), blk, 0, stream>>>(e_src, e_dst, dinv, offs, cur, csr, E);

  // layer 1 GEMM (gather + K=128), grid-stride 2 tiles/block
  k_mm1<<<dim3((ntiles + 1) / 2), blk, 0, stream>>>(x_ids, emb, W1, bufA, N, ntiles);
  // fused conv1+mm2, conv2+mm3, conv3
  k_agg_mm<false><<<dim3(1024), blk, 0, stream>>>(bufA, csr, offs, dinv, b1, W2, bufB, N);
  k_agg_mm<false><<<dim3(1024), blk, 0, stream>>>(bufB, csr, offs, dinv, b2, W3, bufA, N);
  k_agg_mm<true><<<dim3(1024), blk, 0, stream>>>(bufA, csr, offs, dinv, b3, nullptr, bufB, N);

  // pool + MLP head
  k_pool<<<dim3(G), blk, 0, stream>>>(bufB, batch, N, Wf1, bf1, Wf2, bf2, out);
}

// Round 3
// 641.546 us; speedup vs baseline: 2.8196x; 2.8196x over previous
//
#include <hip/hip_runtime.h>
#include <hip/hip_bf16.h>

// GCN, bf16 node features + fp32 accumulation.
//  CSR build -> k_mm1 (gather GEMM, K=128, W in 64 VGPRs x 2 passes)
//  3x k_agg (per-node gather, bf16 rows = 1 cacheline/edge)
//  2x k_mm64 (K=64 GEMM, W in 64 VGPRs, broadcast global X loads, no LDS)
//  k_pool (mean pool + MLP + sigmoid)

typedef unsigned short u16;
typedef unsigned int u32;

__device__ __forceinline__ float bf2f(u16 u) {
  return __uint_as_float(((u32)u) << 16);
}
__device__ __forceinline__ u16 f2bf(float f) {
  u32 x = __float_as_uint(f);
  return (u16)((x + 0x7fffu + ((x >> 16) & 1u)) >> 16);  // RNE
}
__device__ __forceinline__ void unpk(u32 u, float& a, float& b) {
  a = __uint_as_float(u << 16);
  b = __uint_as_float(u & 0xffff0000u);
}

// ---------------- CSR build ----------------
__global__ __launch_bounds__(256) void k_zero(int* __restrict__ p, int n) {
  int i = blockIdx.x * blockDim.x + threadIdx.x;
  for (; i < n; i += gridDim.x * blockDim.x) p[i] = 0;
}

__global__ __launch_bounds__(256) void k_count(const int* __restrict__ dst, int* __restrict__ cnt, int e_count) {
  int e = blockIdx.x * blockDim.x + threadIdx.x;
  if (e < e_count) atomicAdd(&cnt[dst[e]], 1);
}

__global__ __launch_bounds__(256) void k_scan1(const int* __restrict__ cnt, int n, int* __restrict__ bsum) {
  __shared__ int s[256];
  int b = blockIdx.x, t = threadIdx.x;
  int base = b * 1024;
  int sum = 0;
  #pragma unroll
  for (int i = 0; i < 4; ++i) {
    int idx = base + t + i * 256;
    if (idx < n) sum += cnt[idx];
  }
  s[t] = sum; __syncthreads();
  for (int off = 128; off > 0; off >>= 1) {
    if (t < off) s[t] += s[t + off];
    __syncthreads();
  }
  if (t == 0) bsum[b] = s[0];
}

__global__ __launch_bounds__(128) void k_scan2(int* __restrict__ bsum, int nb, int* __restrict__ total_out) {
  __shared__ int sh[128];
  int t = threadIdx.x;
  sh[t] = (t < nb) ? bsum[t] : 0;
  __syncthreads();
  for (int off = 1; off < 128; off <<= 1) {
    int x = sh[t];
    int y = (t >= off) ? sh[t - off] : 0;
    __syncthreads();
    sh[t] = x + y;
    __syncthreads();
  }
  if (t < nb) bsum[t] = (t == 0) ? 0 : sh[t - 1];
  if (t == 0) *total_out = sh[127];
}

__global__ __launch_bounds__(256) void k_scan3(const int* __restrict__ cnt, int n,
                                               const int* __restrict__ bsum_ex, int* __restrict__ offsets,
                                               float* __restrict__ dinv) {
  __shared__ int sh[256];
  int b = blockIdx.x, t = threadIdx.x;
  int base = b * 1024 + t * 4;
  int v0 = (base + 0 < n) ? cnt[base + 0] : 0;
  int v1 = (base + 1 < n) ? cnt[base + 1] : 0;
  int v2 = (base + 2 < n) ? cnt[base + 2] : 0;
  int v3 = (base + 3 < n) ? cnt[base + 3] : 0;
  if (base + 0 < n) dinv[base + 0] = rsqrtf((float)v0 + 1.0f);
  if (base + 1 < n) dinv[base + 1] = rsqrtf((float)v1 + 1.0f);
  if (base + 2 < n) dinv[base + 2] = rsqrtf((float)v2 + 1.0f);
  if (base + 3 < n) dinv[base + 3] = rsqrtf((float)v3 + 1.0f);
  sh[t] = v0 + v1 + v2 + v3;
  __syncthreads();
  for (int off = 1; off < 256; off <<= 1) {
    int x = sh[t];
    int y = (t >= off) ? sh[t - off] : 0;
    __syncthreads();
    sh[t] = x + y;
    __syncthreads();
  }
  int run = bsum_ex[b] + ((t == 0) ? 0 : sh[t - 1]);
  if (base + 0 < n) offsets[base + 0] = run; run += v0;
  if (base + 1 < n) offsets[base + 1] = run; run += v1;
  if (base + 2 < n) offsets[base + 2] = run; run += v2;
  if (base + 3 < n) offsets[base + 3] = run;
}

__global__ __launch_bounds__(256) void k_scatter(const int* __restrict__ src, const int* __restrict__ dst,
                                                 const float* __restrict__ dinv, const int* __restrict__ offsets,
                                                 int* __restrict__ cursor, int2* __restrict__ csr, int e_count) {
  int e = blockIdx.x * blockDim.x + threadIdx.x;
  if (e >= e_count) return;
  int s = src[e], d = dst[e];
  int pos = offsets[d] + atomicAdd(&cursor[d], 1);
  csr[pos] = make_int2(s, __float_as_int(dinv[s] * dinv[d]));
}

// ---------------- layer-1 GEMM: out[r][j] = sum_k emb[ids[r]][k] * W1[k][j] ----------------
// lane = j. K=128 split into two 64-wide passes; W half in 64 VGPRs (reloaded from
// L1 per 16-row batch). X read as broadcast global float4 (no LDS, no barriers).
__global__ __launch_bounds__(256) void k_mm1(const int* __restrict__ ids,
                                             const float* __restrict__ emb,
                                             const float* __restrict__ W1,
                                             u16* __restrict__ out, int n) {
  const int lane = threadIdx.x & 63;
  const int wid = blockIdx.x * 4 + (threadIdx.x >> 6);
  const int nw = gridDim.x * 4;
  const int ng = (n + 15) >> 4;

  for (int g = wid; g < ng; g += nw) {
    const int r0 = g << 4;
    float acc[16];
    #pragma unroll
    for (int i = 0; i < 16; ++i) acc[i] = 0.f;

    #pragma unroll
    for (int kh = 0; kh < 2; ++kh) {
      float wr[64];
      #pragma unroll
      for (int k = 0; k < 64; ++k) wr[k] = W1[(kh * 64 + k) * 64 + lane];
      #pragma unroll 4
      for (int i = 0; i < 16; ++i) {
        int r = r0 + i;
        int rid = (r < n) ? ids[r] : 0;
        const float4* xp = reinterpret_cast<const float4*>(emb + (size_t)rid * 128 + kh * 64);
        float a = 0.f;
        #pragma unroll
        for (int c = 0; c < 16; ++c) {
          float4 xv = xp[c];  // broadcast: all lanes same addr
          a = fmaf(xv.x, wr[c * 4 + 0], a);
          a = fmaf(xv.y, wr[c * 4 + 1], a);
          a = fmaf(xv.z, wr[c * 4 + 2], a);
          a = fmaf(xv.w, wr[c * 4 + 3], a);
        }
        acc[i] += a;
      }
    }
    #pragma unroll
    for (int i = 0; i < 16; ++i) {
      int r = r0 + i;
      if (r < n) out[(size_t)r * 64 + lane] = f2bf(acc[i]);
    }
  }
}

// ---------------- K=64 GEMM: out[r][j] = sum_k X[r][k] * W[k][j] ----------------
// lane = j, W in 64 VGPRs, bf16 X read as broadcast uint4 (8 vals / load).
__global__ __launch_bounds__(256) void k_mm64(const u16* __restrict__ X,
                                              const float* __restrict__ W,
                                              u16* __restrict__ out, int n) {
  const int lane = threadIdx.x & 63;
  const int wid = blockIdx.x * 4 + (threadIdx.x >> 6);
  const int nw = gridDim.x * 4;
  float wr[64];
  #pragma unroll
  for (int k = 0; k < 64; ++k) wr[k] = W[k * 64 + lane];

  const int ng = (n + 3) >> 2;
  for (int g = wid; g < ng; g += nw) {
    const int r0 = g << 2;
    #pragma unroll
    for (int i = 0; i < 4; ++i) {
      int r = r0 + i;
      if (r >= n) break;
      const uint4* xp = reinterpret_cast<const uint4*>(X + (size_t)r * 64);
      float a = 0.f;
      #pragma unroll
      for (int c = 0; c < 8; ++c) {
        uint4 u = xp[c];  // broadcast, 8 bf16
        float f0, f1, f2, f3, f4, f5, f6, f7;
        unpk(u.x, f0, f1); unpk(u.y, f2, f3);
        unpk(u.z, f4, f5); unpk(u.w, f6, f7);
        a = fmaf(f0, wr[c * 8 + 0], a); a = fmaf(f1, wr[c * 8 + 1], a);
        a = fmaf(f2, wr[c * 8 + 2], a); a = fmaf(f3, wr[c * 8 + 3], a);
        a = fmaf(f4, wr[c * 8 + 4], a); a = fmaf(f5, wr[c * 8 + 5], a);
        a = fmaf(f6, wr[c * 8 + 6], a); a = fmaf(f7, wr[c * 8 + 7], a);
      }
      out[(size_t)r * 64 + lane] = f2bf(a);
    }
  }
}

// ---------------- aggregation: out[v] = relu(xw[v]*dinv^2 + b + sum coef*xw[src]) ----------------
// one wave per node, lane = feature; bf16 row = 128 B = 1 cacheline per edge.
__global__ __launch_bounds__(256) void k_agg(const u16* __restrict__ xw, const int2* __restrict__ csr,
                                             const int* __restrict__ offs, const float* __restrict__ dinv,
                                             const float* __restrict__ bias, u16* __restrict__ out, int n) {
  int v = blockIdx.x * 4 + (threadIdx.x >> 6);
  int lane = threadIdx.x & 63;
  if (v >= n) return;
  float di = dinv[v];
  float acc = fmaf(bf2f(xw[(size_t)v * 64 + lane]), di * di, bias[lane]);
  int e = offs[v];
  const int hi = offs[v + 1];
  for (; e + 4 <= hi; e += 4) {
    int2 r0 = csr[e], r1 = csr[e + 1], r2 = csr[e + 2], r3 = csr[e + 3];
    float v0 = bf2f(xw[(size_t)r0.x * 64 + lane]);
    float v1 = bf2f(xw[(size_t)r1.x * 64 + lane]);
    float v2 = bf2f(xw[(size_t)r2.x * 64 + lane]);
    float v3 = bf2f(xw[(size_t)r3.x * 64 + lane]);
    acc = fmaf(v0, __int_as_float(r0.y), acc);
    acc = fmaf(v1, __int_as_float(r1.y), acc);
    acc = fmaf(v2, __int_as_float(r2.y), acc);
    acc = fmaf(v3, __int_as_float(r3.y), acc);
  }
  for (; e < hi; ++e) {
    int2 r = csr[e];
    acc = fmaf(bf2f(xw[(size_t)r.x * 64 + lane]), __int_as_float(r.y), acc);
  }
  out[(size_t)v * 64 + lane] = f2bf(fmaxf(acc, 0.f));
}

// ---------------- pooling + MLP head + sigmoid ----------------
__global__ __launch_bounds__(256) void k_pool(const u16* __restrict__ x, const int* __restrict__ batch, int n,
                                              const float* __restrict__ Wf1, const float* __restrict__ bf1,
                                              const float* __restrict__ Wf2, const float* __restrict__ bf2,
                                              float* __restrict__ out) {
  int g = blockIdx.x;
  int tid = threadIdx.x, lane = tid & 63, w = tid >> 6;
  int a = 0, b = n;
  while (a < b) { int m = (a + b) >> 1; if (batch[m] < g) a = m + 1; else b = m; }
  int lo = a;
  b = n;
  while (a < b) { int m = (a + b) >> 1; if (batch[m] < g + 1) a = m + 1; else b = m; }
  int hi = a;

  float acc = 0.f;
  for (int r = lo + w; r < hi; r += 4) acc += bf2f(x[(size_t)r * 64 + lane]);
  __shared__ float red[4][64];
  __shared__ float mean[64];
  red[w][lane] = acc;
  __syncthreads();
  if (w == 0) {
    float s = red[0][lane] + red[1][lane] + red[2][lane] + red[3][lane];
    mean[lane] = s / fmaxf((float)(hi - lo), 1.0f);
  }
  __syncthreads();
  if (w == 0) {
    float h = bf1[lane];
    #pragma unroll
    for (int k = 0; k < 64; ++k) h = fmaf(mean[k], Wf1[k * 64 + lane], h);
    h = fmaxf(h, 0.f);
    float vv = h * Wf2[lane];
    for (int off = 32; off > 0; off >>= 1) vv += __shfl_down(vv, off, 64);
    if (lane == 0) out[g] = 1.0f / (1.0f + expf(-(vv + bf2[0])));
  }
}

static inline char* align256(char* p) {
  return (char*)(((uintptr_t)p + 255) & ~(uintptr_t)255);
}

extern "C" void kernel_launch(void* const* d_in, const int* in_sizes, int n_in,
                              void* d_out, int out_size, void* d_ws, size_t ws_size,
                              hipStream_t stream) {
  const int*   x_ids = (const int*)d_in[0];
  const int*   edge  = (const int*)d_in[1];
  const int*   batch = (const int*)d_in[2];
  const float* emb   = (const float*)d_in[3];
  const float* W1    = (const float*)d_in[4];
  const float* b1    = (const float*)d_in[5];
  const float* W2    = (const float*)d_in[6];
  const float* b2    = (const float*)d_in[7];
  const float* W3    = (const float*)d_in[8];
  const float* b3    = (const float*)d_in[9];
  const float* Wf1   = (const float*)d_in[10];
  const float* bf1   = (const float*)d_in[11];
  const float* Wf2   = (const float*)d_in[12];
  const float* bf2   = (const float*)d_in[13];
  float* out = (float*)d_out;

  const int N = in_sizes[0];
  const int E = in_sizes[1] / 2;
  const int G = out_size;
  const int* e_src = edge;
  const int* e_dst = edge + E;

  // workspace layout (bf16 feature buffers)
  char* p = (char*)d_ws;
  u16*   bufA = (u16*)p;              p = align256(p + (size_t)N * 64 * 2);
  u16*   bufB = (u16*)p;              p = align256(p + (size_t)N * 64 * 2);
  int2*  csr  = (int2*)p;             p = align256(p + (size_t)E * 8);
  float* dinv = (float*)p;            p = align256(p + (size_t)N * 4);
  int*   cntcur = (int*)p;            p = align256(p + (size_t)2 * N * 4);
  int*   offs = (int*)p;              p = align256(p + (size_t)(N + 1) * 4);
  int*   bsum = (int*)p;              p = align256(p + (size_t)1024 * 4);
  int*   cnt = cntcur;
  int*   cur = cntcur + N;
  (void)ws_size; (void)n_in;

  const int nb_scan = (N + 1023) / 1024;  // 98 for N=100000 (<=128)
  dim3 blk(256);

  // CSR build
  k_zero<<<dim3(256), blk, 0, stream>>>(cntcur, 2 * N);
  k_count<<<dim3((E + 255) / 256), blk, 0, stream>>>(e_dst, cnt, E);
  k_scan1<<<dim3(nb_scan), blk, 0, stream>>>(cnt, N, bsum);
  k_scan2<<<dim3(1), dim3(128), 0, stream>>>(bsum, nb_scan, offs + N);
  k_scan3<<<dim3(nb_scan), blk, 0, stream>>>(cnt, N, bsum, offs, dinv);
  k_scatter<<<dim3((E + 255) / 256), blk, 0, stream>>>(e_src, e_dst, dinv, offs, cur, csr, E);

  const int agg_grid = (N + 3) / 4;

  // layer 1
  k_mm1<<<dim3(512), blk, 0, stream>>>(x_ids, emb, W1, bufA, N);
  k_agg<<<dim3(agg_grid), blk, 0, stream>>>(bufA, csr, offs, dinv, b1, bufB, N);
  // layer 2
  k_mm64<<<dim3(1024), blk, 0, stream>>>(bufB, W2, bufA, N);
  k_agg<<<dim3(agg_grid), blk, 0, stream>>>(bufA, csr, offs, dinv, b2, bufB, N);
  // layer 3
  k_mm64<<<dim3(1024), blk, 0, stream>>>(bufB, W3, bufA, N);
  k_agg<<<dim3(agg_grid), blk, 0, stream>>>(bufA, csr, offs, dinv, b3, bufB, N);

  // pool + MLP head
  k_pool<<<dim3(G), blk, 0, stream>>>(bufB, batch, N, Wf1, bf1, Wf2, bf2, out);
}

// Round 4
// 571.658 us; speedup vs baseline: 3.1643x; 1.1223x over previous
//
#include <hip/hip_runtime.h>
#include <hip/hip_bf16.h>

// GCN, bf16 node features + fp32 accumulation.
//  CSR build -> k_mm1 (lane=row gather GEMM, scalar-pipe W)
//  3x k_agg<FINAL> (per-node gather + fused next-layer GEMM via v_readlane)
//  k_pool (mean pool + MLP + sigmoid)

typedef unsigned short u16;
typedef unsigned int u32;

__device__ __forceinline__ float bf2f(u16 u) {
  return __uint_as_float(((u32)u) << 16);
}
__device__ __forceinline__ u16 f2bf(float f) {
  u32 x = __float_as_uint(f);
  return (u16)((x + 0x7fffu + ((x >> 16) & 1u)) >> 16);  // RNE
}

// ---------------- CSR build ----------------
__global__ __launch_bounds__(256) void k_zero(int* __restrict__ p, int n) {
  int i = blockIdx.x * blockDim.x + threadIdx.x;
  for (; i < n; i += gridDim.x * blockDim.x) p[i] = 0;
}

__global__ __launch_bounds__(256) void k_count(const int* __restrict__ dst, int* __restrict__ cnt, int e_count) {
  int e = blockIdx.x * blockDim.x + threadIdx.x;
  if (e < e_count) atomicAdd(&cnt[dst[e]], 1);
}

__global__ __launch_bounds__(256) void k_scan1(const int* __restrict__ cnt, int n, int* __restrict__ bsum) {
  __shared__ int s[256];
  int b = blockIdx.x, t = threadIdx.x;
  int base = b * 1024;
  int sum = 0;
  #pragma unroll
  for (int i = 0; i < 4; ++i) {
    int idx = base + t + i * 256;
    if (idx < n) sum += cnt[idx];
  }
  s[t] = sum; __syncthreads();
  for (int off = 128; off > 0; off >>= 1) {
    if (t < off) s[t] += s[t + off];
    __syncthreads();
  }
  if (t == 0) bsum[b] = s[0];
}

__global__ __launch_bounds__(128) void k_scan2(int* __restrict__ bsum, int nb, int* __restrict__ total_out) {
  __shared__ int sh[128];
  int t = threadIdx.x;
  sh[t] = (t < nb) ? bsum[t] : 0;
  __syncthreads();
  for (int off = 1; off < 128; off <<= 1) {
    int x = sh[t];
    int y = (t >= off) ? sh[t - off] : 0;
    __syncthreads();
    sh[t] = x + y;
    __syncthreads();
  }
  if (t < nb) bsum[t] = (t == 0) ? 0 : sh[t - 1];
  if (t == 0) *total_out = sh[127];
}

__global__ __launch_bounds__(256) void k_scan3(const int* __restrict__ cnt, int n,
                                               const int* __restrict__ bsum_ex, int* __restrict__ offsets,
                                               float* __restrict__ dinv) {
  __shared__ int sh[256];
  int b = blockIdx.x, t = threadIdx.x;
  int base = b * 1024 + t * 4;
  int v0 = (base + 0 < n) ? cnt[base + 0] : 0;
  int v1 = (base + 1 < n) ? cnt[base + 1] : 0;
  int v2 = (base + 2 < n) ? cnt[base + 2] : 0;
  int v3 = (base + 3 < n) ? cnt[base + 3] : 0;
  if (base + 0 < n) dinv[base + 0] = rsqrtf((float)v0 + 1.0f);
  if (base + 1 < n) dinv[base + 1] = rsqrtf((float)v1 + 1.0f);
  if (base + 2 < n) dinv[base + 2] = rsqrtf((float)v2 + 1.0f);
  if (base + 3 < n) dinv[base + 3] = rsqrtf((float)v3 + 1.0f);
  sh[t] = v0 + v1 + v2 + v3;
  __syncthreads();
  for (int off = 1; off < 256; off <<= 1) {
    int x = sh[t];
    int y = (t >= off) ? sh[t - off] : 0;
    __syncthreads();
    sh[t] = x + y;
    __syncthreads();
  }
  int run = bsum_ex[b] + ((t == 0) ? 0 : sh[t - 1]);
  if (base + 0 < n) offsets[base + 0] = run; run += v0;
  if (base + 1 < n) offsets[base + 1] = run; run += v1;
  if (base + 2 < n) offsets[base + 2] = run; run += v2;
  if (base + 3 < n) offsets[base + 3] = run;
}

__global__ __launch_bounds__(256) void k_scatter(const int* __restrict__ src, const int* __restrict__ dst,
                                                 const float* __restrict__ dinv, const int* __restrict__ offsets,
                                                 int* __restrict__ cursor, int2* __restrict__ csr, int e_count) {
  int e = blockIdx.x * blockDim.x + threadIdx.x;
  if (e >= e_count) return;
  int s = src[e], d = dst[e];
  int pos = offsets[d] + atomicAdd(&cursor[d], 1);
  csr[pos] = make_int2(s, __float_as_int(dinv[s] * dinv[d]));
}

// ---------------- layer-1 GEMM: out[r][j] = sum_k emb[ids[r]][k] * W1[k][j] ----------------
// lane = row (64 rows per wave, 1 wave per block). Each lane streams ITS OWN
// gathered emb row (parallel per-lane float4 loads); W addresses are
// lane-invariant -> scalar-pipe loads. Two j-passes of 32 accumulators.
__global__ __launch_bounds__(64) void k_mm1(const int* __restrict__ ids,
                                            const float* __restrict__ emb,
                                            const float* __restrict__ W1,
                                            u16* __restrict__ out, int n) {
  const int lane = threadIdx.x;
  const int r = blockIdx.x * 64 + lane;
  const int rid = ids[(r < n) ? r : (n - 1)];
  const float4* __restrict__ xrow = reinterpret_cast<const float4*>(emb + (size_t)rid * 128);

  #pragma unroll 1
  for (int jb = 0; jb < 2; ++jb) {
    const float* __restrict__ Wb = W1 + jb * 32;
    float acc[32];
    #pragma unroll
    for (int j = 0; j < 32; ++j) acc[j] = 0.f;
    #pragma unroll 4
    for (int k4 = 0; k4 < 32; ++k4) {
      float4 xv = xrow[k4];
      const float* __restrict__ w0 = Wb + (k4 * 4) * 64;
      #pragma unroll
      for (int j = 0; j < 32; ++j) {
        acc[j] = fmaf(xv.x, w0[j], acc[j]);
        acc[j] = fmaf(xv.y, w0[64 + j], acc[j]);
        acc[j] = fmaf(xv.z, w0[128 + j], acc[j]);
        acc[j] = fmaf(xv.w, w0[192 + j], acc[j]);
      }
    }
    if (r < n) {
      u16* op = out + (size_t)r * 64 + jb * 32;
      #pragma unroll
      for (int j8 = 0; j8 < 4; ++j8) {
        uint4 pk;
        pk.x = ((u32)f2bf(acc[j8 * 8 + 1]) << 16) | f2bf(acc[j8 * 8 + 0]);
        pk.y = ((u32)f2bf(acc[j8 * 8 + 3]) << 16) | f2bf(acc[j8 * 8 + 2]);
        pk.z = ((u32)f2bf(acc[j8 * 8 + 5]) << 16) | f2bf(acc[j8 * 8 + 4]);
        pk.w = ((u32)f2bf(acc[j8 * 8 + 7]) << 16) | f2bf(acc[j8 * 8 + 6]);
        *reinterpret_cast<uint4*>(op + j8 * 8) = pk;
      }
    }
  }
}

// ---------------- fused aggregation + next-layer GEMM ----------------
// Phase 1 (lane=feature k): h = relu(xw[v]*dinv^2 + b + sum coef*xw[src]).
// Phase 2 (lane=out col j): out_j = sum_k readlane(h,k) * wr[k]  (W in 64 VGPRs).
template <bool FINAL>
__global__ __launch_bounds__(256) void k_agg(const u16* __restrict__ xw, const int2* __restrict__ csr,
                                             const int* __restrict__ offs, const float* __restrict__ dinv,
                                             const float* __restrict__ bias, const float* __restrict__ Wn,
                                             u16* __restrict__ out, int n) {
  const int lane = threadIdx.x & 63;
  const int w = threadIdx.x >> 6;
  float wr[64];
  if constexpr (!FINAL) {
    #pragma unroll
    for (int k = 0; k < 64; ++k) wr[k] = Wn[k * 64 + lane];
  }
  const float bl = bias[lane];

  for (int v = blockIdx.x * 4 + w; v < n; v += gridDim.x * 4) {
    float di = dinv[v];
    float acc = fmaf(bf2f(xw[(size_t)v * 64 + lane]), di * di, bl);
    int e = offs[v];
    const int hi = offs[v + 1];
    for (; e + 8 <= hi; e += 8) {
      int2 r0 = csr[e], r1 = csr[e + 1], r2 = csr[e + 2], r3 = csr[e + 3];
      int2 r4 = csr[e + 4], r5 = csr[e + 5], r6 = csr[e + 6], r7 = csr[e + 7];
      float v0 = bf2f(xw[(size_t)r0.x * 64 + lane]);
      float v1 = bf2f(xw[(size_t)r1.x * 64 + lane]);
      float v2 = bf2f(xw[(size_t)r2.x * 64 + lane]);
      float v3 = bf2f(xw[(size_t)r3.x * 64 + lane]);
      float v4 = bf2f(xw[(size_t)r4.x * 64 + lane]);
      float v5 = bf2f(xw[(size_t)r5.x * 64 + lane]);
      float v6 = bf2f(xw[(size_t)r6.x * 64 + lane]);
      float v7 = bf2f(xw[(size_t)r7.x * 64 + lane]);
      acc = fmaf(v0, __int_as_float(r0.y), acc);
      acc = fmaf(v1, __int_as_float(r1.y), acc);
      acc = fmaf(v2, __int_as_float(r2.y), acc);
      acc = fmaf(v3, __int_as_float(r3.y), acc);
      acc = fmaf(v4, __int_as_float(r4.y), acc);
      acc = fmaf(v5, __int_as_float(r5.y), acc);
      acc = fmaf(v6, __int_as_float(r6.y), acc);
      acc = fmaf(v7, __int_as_float(r7.y), acc);
    }
    for (; e < hi; ++e) {
      int2 r = csr[e];
      acc = fmaf(bf2f(xw[(size_t)r.x * 64 + lane]), __int_as_float(r.y), acc);
    }
    float h = fmaxf(acc, 0.f);
    if constexpr (FINAL) {
      out[(size_t)v * 64 + lane] = f2bf(h);
    } else {
      const int hbits = __float_as_int(h);
      float o = 0.f;
      #pragma unroll
      for (int k = 0; k < 64; ++k) {
        float hk = __int_as_float(__builtin_amdgcn_readlane(hbits, k));
        o = fmaf(hk, wr[k], o);
      }
      out[(size_t)v * 64 + lane] = f2bf(o);
    }
  }
}

// ---------------- pooling + MLP head + sigmoid ----------------
__global__ __launch_bounds__(256) void k_pool(const u16* __restrict__ x, const int* __restrict__ batch, int n,
                                              const float* __restrict__ Wf1, const float* __restrict__ bf1,
                                              const float* __restrict__ Wf2, const float* __restrict__ bf2,
                                              float* __restrict__ out) {
  int g = blockIdx.x;
  int tid = threadIdx.x, lane = tid & 63, w = tid >> 6;
  int a = 0, b = n;
  while (a < b) { int m = (a + b) >> 1; if (batch[m] < g) a = m + 1; else b = m; }
  int lo = a;
  b = n;
  while (a < b) { int m = (a + b) >> 1; if (batch[m] < g + 1) a = m + 1; else b = m; }
  int hi = a;

  float acc = 0.f;
  for (int r = lo + w; r < hi; r += 4) acc += bf2f(x[(size_t)r * 64 + lane]);
  __shared__ float red[4][64];
  __shared__ float mean[64];
  red[w][lane] = acc;
  __syncthreads();
  if (w == 0) {
    float s = red[0][lane] + red[1][lane] + red[2][lane] + red[3][lane];
    mean[lane] = s / fmaxf((float)(hi - lo), 1.0f);
  }
  __syncthreads();
  if (w == 0) {
    float h = bf1[lane];
    #pragma unroll
    for (int k = 0; k < 64; ++k) h = fmaf(mean[k], Wf1[k * 64 + lane], h);
    h = fmaxf(h, 0.f);
    float vv = h * Wf2[lane];
    for (int off = 32; off > 0; off >>= 1) vv += __shfl_down(vv, off, 64);
    if (lane == 0) out[g] = 1.0f / (1.0f + expf(-(vv + bf2[0])));
  }
}

static inline char* align256(char* p) {
  return (char*)(((uintptr_t)p + 255) & ~(uintptr_t)255);
}

extern "C" void kernel_launch(void* const* d_in, const int* in_sizes, int n_in,
                              void* d_out, int out_size, void* d_ws, size_t ws_size,
                              hipStream_t stream) {
  const int*   x_ids = (const int*)d_in[0];
  const int*   edge  = (const int*)d_in[1];
  const int*   batch = (const int*)d_in[2];
  const float* emb   = (const float*)d_in[3];
  const float* W1    = (const float*)d_in[4];
  const float* b1    = (const float*)d_in[5];
  const float* W2    = (const float*)d_in[6];
  const float* b2    = (const float*)d_in[7];
  const float* W3    = (const float*)d_in[8];
  const float* b3    = (const float*)d_in[9];
  const float* Wf1   = (const float*)d_in[10];
  const float* bf1   = (const float*)d_in[11];
  const float* Wf2   = (const float*)d_in[12];
  const float* bf2   = (const float*)d_in[13];
  float* out = (float*)d_out;

  const int N = in_sizes[0];
  const int E = in_sizes[1] / 2;
  const int G = out_size;
  const int* e_src = edge;
  const int* e_dst = edge + E;

  // workspace layout (bf16 feature buffers)
  char* p = (char*)d_ws;
  u16*   bufA = (u16*)p;              p = align256(p + (size_t)N * 64 * 2);
  u16*   bufB = (u16*)p;              p = align256(p + (size_t)N * 64 * 2);
  int2*  csr  = (int2*)p;             p = align256(p + (size_t)E * 8);
  float* dinv = (float*)p;            p = align256(p + (size_t)N * 4);
  int*   cntcur = (int*)p;            p = align256(p + (size_t)2 * N * 4);
  int*   offs = (int*)p;              p = align256(p + (size_t)(N + 1) * 4);
  int*   bsum = (int*)p;              p = align256(p + (size_t)1024 * 4);
  int*   cnt = cntcur;
  int*   cur = cntcur + N;
  (void)ws_size; (void)n_in;

  const int nb_scan = (N + 1023) / 1024;  // 98 for N=100000 (<=128)
  dim3 blk(256);

  // CSR build
  k_zero<<<dim3(256), blk, 0, stream>>>(cntcur, 2 * N);
  k_count<<<dim3((E + 255) / 256), blk, 0, stream>>>(e_dst, cnt, E);
  k_scan1<<<dim3(nb_scan), blk, 0, stream>>>(cnt, N, bsum);
  k_scan2<<<dim3(1), dim3(128), 0, stream>>>(bsum, nb_scan, offs + N);
  k_scan3<<<dim3(nb_scan), blk, 0, stream>>>(cnt, N, bsum, offs, dinv);
  k_scatter<<<dim3((E + 255) / 256), blk, 0, stream>>>(e_src, e_dst, dinv, offs, cur, csr, E);

  // layer 1 GEMM: 1 wave per 64 rows
  k_mm1<<<dim3((N + 63) / 64), dim3(64), 0, stream>>>(x_ids, emb, W1, bufA, N);
  // fused conv+next-GEMM chain
  k_agg<false><<<dim3(4096), blk, 0, stream>>>(bufA, csr, offs, dinv, b1, W2, bufB, N);
  k_agg<false><<<dim3(4096), blk, 0, stream>>>(bufB, csr, offs, dinv, b2, W3, bufA, N);
  k_agg<true><<<dim3(4096), blk, 0, stream>>>(bufA, csr, offs, dinv, b3, nullptr, bufB, N);

  // pool + MLP head
  k_pool<<<dim3(G), blk, 0, stream>>>(bufB, batch, N, Wf1, bf1, Wf2, bf2, out);
}

// Round 5
// 513.545 us; speedup vs baseline: 3.5224x; 1.1132x over previous
//
#include <hip/hip_runtime.h>
#include <hip/hip_bf16.h>

// GCN, bf16 node features + fp32 accumulation.
//  CSR build -> k_mm1 (lane=row gather GEMM)
//  3x k_agg<FINAL>: 4 nodes/wave, chunk-coalesced csr loads + readlane
//                   distribution (max outstanding gathers), fused next-W GEMM.
//  k_pool (mean pool + MLP + sigmoid)

typedef unsigned short u16;
typedef unsigned int u32;

__device__ __forceinline__ float bf2f(u16 u) {
  return __uint_as_float(((u32)u) << 16);
}
__device__ __forceinline__ u16 f2bf(float f) {
  u32 x = __float_as_uint(f);
  return (u16)((x + 0x7fffu + ((x >> 16) & 1u)) >> 16);  // RNE
}

// ---------------- CSR build ----------------
__global__ __launch_bounds__(256) void k_zero(int* __restrict__ p, int n) {
  int i = blockIdx.x * blockDim.x + threadIdx.x;
  for (; i < n; i += gridDim.x * blockDim.x) p[i] = 0;
}

__global__ __launch_bounds__(256) void k_count(const int* __restrict__ dst, int* __restrict__ cnt, int e_count) {
  int e = blockIdx.x * blockDim.x + threadIdx.x;
  if (e < e_count) atomicAdd(&cnt[dst[e]], 1);
}

__global__ __launch_bounds__(256) void k_scan1(const int* __restrict__ cnt, int n, int* __restrict__ bsum) {
  __shared__ int s[256];
  int b = blockIdx.x, t = threadIdx.x;
  int base = b * 1024;
  int sum = 0;
  #pragma unroll
  for (int i = 0; i < 4; ++i) {
    int idx = base + t + i * 256;
    if (idx < n) sum += cnt[idx];
  }
  s[t] = sum; __syncthreads();
  for (int off = 128; off > 0; off >>= 1) {
    if (t < off) s[t] += s[t + off];
    __syncthreads();
  }
  if (t == 0) bsum[b] = s[0];
}

__global__ __launch_bounds__(128) void k_scan2(int* __restrict__ bsum, int nb, int* __restrict__ total_out) {
  __shared__ int sh[128];
  int t = threadIdx.x;
  sh[t] = (t < nb) ? bsum[t] : 0;
  __syncthreads();
  for (int off = 1; off < 128; off <<= 1) {
    int x = sh[t];
    int y = (t >= off) ? sh[t - off] : 0;
    __syncthreads();
    sh[t] = x + y;
    __syncthreads();
  }
  if (t < nb) bsum[t] = (t == 0) ? 0 : sh[t - 1];
  if (t == 0) *total_out = sh[127];
}

__global__ __launch_bounds__(256) void k_scan3(const int* __restrict__ cnt, int n,
                                               const int* __restrict__ bsum_ex, int* __restrict__ offsets,
                                               float* __restrict__ dinv) {
  __shared__ int sh[256];
  int b = blockIdx.x, t = threadIdx.x;
  int base = b * 1024 + t * 4;
  int v0 = (base + 0 < n) ? cnt[base + 0] : 0;
  int v1 = (base + 1 < n) ? cnt[base + 1] : 0;
  int v2 = (base + 2 < n) ? cnt[base + 2] : 0;
  int v3 = (base + 3 < n) ? cnt[base + 3] : 0;
  if (base + 0 < n) dinv[base + 0] = rsqrtf((float)v0 + 1.0f);
  if (base + 1 < n) dinv[base + 1] = rsqrtf((float)v1 + 1.0f);
  if (base + 2 < n) dinv[base + 2] = rsqrtf((float)v2 + 1.0f);
  if (base + 3 < n) dinv[base + 3] = rsqrtf((float)v3 + 1.0f);
  sh[t] = v0 + v1 + v2 + v3;
  __syncthreads();
  for (int off = 1; off < 256; off <<= 1) {
    int x = sh[t];
    int y = (t >= off) ? sh[t - off] : 0;
    __syncthreads();
    sh[t] = x + y;
    __syncthreads();
  }
  int run = bsum_ex[b] + ((t == 0) ? 0 : sh[t - 1]);
  if (base + 0 < n) offsets[base + 0] = run; run += v0;
  if (base + 1 < n) offsets[base + 1] = run; run += v1;
  if (base + 2 < n) offsets[base + 2] = run; run += v2;
  if (base + 3 < n) offsets[base + 3] = run;
}

__global__ __launch_bounds__(256) void k_scatter(const int* __restrict__ src, const int* __restrict__ dst,
                                                 const float* __restrict__ dinv, const int* __restrict__ offsets,
                                                 int* __restrict__ cursor, int2* __restrict__ csr, int e_count) {
  int e = blockIdx.x * blockDim.x + threadIdx.x;
  if (e >= e_count) return;
  int s = src[e], d = dst[e];
  int pos = offsets[d] + atomicAdd(&cursor[d], 1);
  csr[pos] = make_int2(s, __float_as_int(dinv[s] * dinv[d]));
}

// ---------------- layer-1 GEMM: out[r][j] = sum_k emb[ids[r]][k] * W1[k][j] ----------------
// lane = row; per-lane float4 row streams; W broadcast loads (L1-hot).
__global__ __launch_bounds__(64) void k_mm1(const int* __restrict__ ids,
                                            const float* __restrict__ emb,
                                            const float* __restrict__ W1,
                                            u16* __restrict__ out, int n) {
  const int lane = threadIdx.x;
  const int r = blockIdx.x * 64 + lane;
  const int rid = ids[(r < n) ? r : (n - 1)];
  const float4* __restrict__ xrow = reinterpret_cast<const float4*>(emb + (size_t)rid * 128);

  #pragma unroll 1
  for (int jb = 0; jb < 2; ++jb) {
    const float* __restrict__ Wb = W1 + jb * 32;
    float acc[32];
    #pragma unroll
    for (int j = 0; j < 32; ++j) acc[j] = 0.f;
    #pragma unroll 4
    for (int k4 = 0; k4 < 32; ++k4) {
      float4 xv = xrow[k4];
      const float* __restrict__ w0 = Wb + (k4 * 4) * 64;
      #pragma unroll
      for (int j = 0; j < 32; ++j) {
        acc[j] = fmaf(xv.x, w0[j], acc[j]);
        acc[j] = fmaf(xv.y, w0[64 + j], acc[j]);
        acc[j] = fmaf(xv.z, w0[128 + j], acc[j]);
        acc[j] = fmaf(xv.w, w0[192 + j], acc[j]);
      }
    }
    if (r < n) {
      u16* op = out + (size_t)r * 64 + jb * 32;
      #pragma unroll
      for (int j8 = 0; j8 < 4; ++j8) {
        uint4 pk;
        pk.x = ((u32)f2bf(acc[j8 * 8 + 1]) << 16) | f2bf(acc[j8 * 8 + 0]);
        pk.y = ((u32)f2bf(acc[j8 * 8 + 3]) << 16) | f2bf(acc[j8 * 8 + 2]);
        pk.z = ((u32)f2bf(acc[j8 * 8 + 5]) << 16) | f2bf(acc[j8 * 8 + 4]);
        pk.w = ((u32)f2bf(acc[j8 * 8 + 7]) << 16) | f2bf(acc[j8 * 8 + 6]);
        *reinterpret_cast<uint4*>(op + j8 * 8) = pk;
      }
    }
  }
}

// ---------------- fused aggregation + next-layer GEMM ----------------
// 4 consecutive nodes per wave. Their CSR segments are contiguous: stage up to
// 64 edges with ONE coalesced per-lane int2 load, distribute via v_readlane
// (register op) -> all gathers in a chunk are independent & outstanding.
// Phase 2 (lane = out col j): out_j = sum_k readlane(h,k) * W[k][j].

#define AGG_BATCH8(ACC, O)                                                   \
  {                                                                          \
    float vv_[8], cc_[8];                                                    \
    _Pragma("unroll")                                                        \
    for (int t_ = 0; t_ < 8; ++t_) {                                         \
      int sb_ = __builtin_amdgcn_readlane(cex, (O) + t_);                    \
      cc_[t_] = __int_as_float(__builtin_amdgcn_readlane(cey, (O) + t_));    \
      vv_[t_] = bf2f(xw[(size_t)sb_ * 64 + lane]);                           \
    }                                                                        \
    _Pragma("unroll")                                                        \
    for (int t_ = 0; t_ < 8; ++t_) ACC = fmaf(vv_[t_], cc_[t_], ACC);        \
  }

#define AGG_ONE(ACC, O)                                                      \
  {                                                                          \
    int sb_ = __builtin_amdgcn_readlane(cex, (O));                           \
    float cf_ = __int_as_float(__builtin_amdgcn_readlane(cey, (O)));         \
    ACC = fmaf(bf2f(xw[(size_t)sb_ * 64 + lane]), cf_, ACC);                 \
  }

#define AGG_NODE(ACC, STOP)                                                  \
  {                                                                          \
    int stop_ = (STOP) < chunk_end ? (STOP) : chunk_end;                     \
    for (; pos + 8 <= stop_; pos += 8) AGG_BATCH8(ACC, pos - e)              \
    for (; pos < stop_; ++pos) AGG_ONE(ACC, pos - e)                         \
  }

template <bool FINAL>
__global__ __launch_bounds__(256) void k_agg(const u16* __restrict__ xw, const int2* __restrict__ csr,
                                             const int* __restrict__ offs, const float* __restrict__ dinv,
                                             const float* __restrict__ bias, const float* __restrict__ Wn,
                                             u16* __restrict__ out, int n) {
  const int lane = threadIdx.x & 63;
  const int w = threadIdx.x >> 6;
  const float bl = bias[lane];
  const int ngroups = (n + 3) >> 2;
  const int nwaves = gridDim.x * 4;

  for (int grp = blockIdx.x * 4 + w; grp < ngroups; grp += nwaves) {
    const int v0 = grp * 4;
    const int c1 = (v0 + 1 < n) ? v0 + 1 : n;
    const int c2 = (v0 + 2 < n) ? v0 + 2 : n;
    const int c3 = (v0 + 3 < n) ? v0 + 3 : n;
    const int b0 = offs[v0], b1 = offs[c1], b2 = offs[c2], b3 = offs[c3], b4 = offs[(v0 + 4 < n) ? v0 + 4 : n];

    float d0 = dinv[v0];
    float d1 = dinv[(c1 < n) ? c1 : v0];
    float d2 = dinv[(c2 < n) ? c2 : v0];
    float d3 = dinv[(c3 < n) ? c3 : v0];
    float acc0 = fmaf(bf2f(xw[(size_t)v0 * 64 + lane]), d0 * d0, bl);
    float acc1 = (c1 < n) ? fmaf(bf2f(xw[(size_t)c1 * 64 + lane]), d1 * d1, bl) : 0.f;
    float acc2 = (c2 < n) ? fmaf(bf2f(xw[(size_t)c2 * 64 + lane]), d2 * d2, bl) : 0.f;
    float acc3 = (c3 < n) ? fmaf(bf2f(xw[(size_t)c3 * 64 + lane]), d3 * d3, bl) : 0.f;

    int e = b0;
    int pos = b0;
    while (e < b4) {
      int cnt = b4 - e;
      cnt = (cnt < 64) ? cnt : 64;
      int cex, cey;
      {
        int2 ce = make_int2(0, 0);
        if (lane < cnt) ce = csr[e + lane];
        cex = ce.x; cey = ce.y;
      }
      const int chunk_end = e + cnt;
      AGG_NODE(acc0, b1)
      AGG_NODE(acc1, b2)
      AGG_NODE(acc2, b3)
      AGG_NODE(acc3, b4)
      e = chunk_end;
    }

    float h0 = fmaxf(acc0, 0.f), h1 = fmaxf(acc1, 0.f);
    float h2 = fmaxf(acc2, 0.f), h3 = fmaxf(acc3, 0.f);
    if constexpr (FINAL) {
      out[(size_t)v0 * 64 + lane] = f2bf(h0);
      if (c1 < n) out[(size_t)c1 * 64 + lane] = f2bf(h1);
      if (c2 < n) out[(size_t)c2 * 64 + lane] = f2bf(h2);
      if (c3 < n) out[(size_t)c3 * 64 + lane] = f2bf(h3);
    } else {
      const int hb0 = __float_as_int(h0), hb1 = __float_as_int(h1);
      const int hb2 = __float_as_int(h2), hb3 = __float_as_int(h3);
      float o0 = 0.f, o1 = 0.f, o2 = 0.f, o3 = 0.f;
      #pragma unroll
      for (int k = 0; k < 64; ++k) {
        float wk = Wn[k * 64 + lane];
        o0 = fmaf(__int_as_float(__builtin_amdgcn_readlane(hb0, k)), wk, o0);
        o1 = fmaf(__int_as_float(__builtin_amdgcn_readlane(hb1, k)), wk, o1);
        o2 = fmaf(__int_as_float(__builtin_amdgcn_readlane(hb2, k)), wk, o2);
        o3 = fmaf(__int_as_float(__builtin_amdgcn_readlane(hb3, k)), wk, o3);
      }
      out[(size_t)v0 * 64 + lane] = f2bf(o0);
      if (c1 < n) out[(size_t)c1 * 64 + lane] = f2bf(o1);
      if (c2 < n) out[(size_t)c2 * 64 + lane] = f2bf(o2);
      if (c3 < n) out[(size_t)c3 * 64 + lane] = f2bf(o3);
    }
  }
}

// ---------------- pooling + MLP head + sigmoid ----------------
__global__ __launch_bounds__(256) void k_pool(const u16* __restrict__ x, const int* __restrict__ batch, int n,
                                              const float* __restrict__ Wf1, const float* __restrict__ bf1,
                                              const float* __restrict__ Wf2, const float* __restrict__ bf2,
                                              float* __restrict__ out) {
  int g = blockIdx.x;
  int tid = threadIdx.x, lane = tid & 63, w = tid >> 6;
  int a = 0, b = n;
  while (a < b) { int m = (a + b) >> 1; if (batch[m] < g) a = m + 1; else b = m; }
  int lo = a;
  b = n;
  while (a < b) { int m = (a + b) >> 1; if (batch[m] < g + 1) a = m + 1; else b = m; }
  int hi = a;

  float acc = 0.f;
  for (int r = lo + w; r < hi; r += 4) acc += bf2f(x[(size_t)r * 64 + lane]);
  __shared__ float red[4][64];
  __shared__ float mean[64];
  red[w][lane] = acc;
  __syncthreads();
  if (w == 0) {
    float s = red[0][lane] + red[1][lane] + red[2][lane] + red[3][lane];
    mean[lane] = s / fmaxf((float)(hi - lo), 1.0f);
  }
  __syncthreads();
  if (w == 0) {
    float h = bf1[lane];
    #pragma unroll
    for (int k = 0; k < 64; ++k) h = fmaf(mean[k], Wf1[k * 64 + lane], h);
    h = fmaxf(h, 0.f);
    float vv = h * Wf2[lane];
    for (int off = 32; off > 0; off >>= 1) vv += __shfl_down(vv, off, 64);
    if (lane == 0) out[g] = 1.0f / (1.0f + expf(-(vv + bf2[0])));
  }
}

static inline char* align256(char* p) {
  return (char*)(((uintptr_t)p + 255) & ~(uintptr_t)255);
}

extern "C" void kernel_launch(void* const* d_in, const int* in_sizes, int n_in,
                              void* d_out, int out_size, void* d_ws, size_t ws_size,
                              hipStream_t stream) {
  const int*   x_ids = (const int*)d_in[0];
  const int*   edge  = (const int*)d_in[1];
  const int*   batch = (const int*)d_in[2];
  const float* emb   = (const float*)d_in[3];
  const float* W1    = (const float*)d_in[4];
  const float* b1    = (const float*)d_in[5];
  const float* W2    = (const float*)d_in[6];
  const float* b2    = (const float*)d_in[7];
  const float* W3    = (const float*)d_in[8];
  const float* b3    = (const float*)d_in[9];
  const float* Wf1   = (const float*)d_in[10];
  const float* bf1   = (const float*)d_in[11];
  const float* Wf2   = (const float*)d_in[12];
  const float* bf2   = (const float*)d_in[13];
  float* out = (float*)d_out;

  const int N = in_sizes[0];
  const int E = in_sizes[1] / 2;
  const int G = out_size;
  const int* e_src = edge;
  const int* e_dst = edge + E;

  // workspace layout (bf16 feature buffers)
  char* p = (char*)d_ws;
  u16*   bufA = (u16*)p;              p = align256(p + (size_t)N * 64 * 2);
  u16*   bufB = (u16*)p;              p = align256(p + (size_t)N * 64 * 2);
  int2*  csr  = (int2*)p;             p = align256(p + (size_t)(E + 64) * 8);
  float* dinv = (float*)p;            p = align256(p + (size_t)N * 4);
  int*   cntcur = (int*)p;            p = align256(p + (size_t)2 * N * 4);
  int*   offs = (int*)p;              p = align256(p + (size_t)(N + 1) * 4);
  int*   bsum = (int*)p;              p = align256(p + (size_t)1024 * 4);
  int*   cnt = cntcur;
  int*   cur = cntcur + N;
  (void)ws_size; (void)n_in;

  const int nb_scan = (N + 1023) / 1024;  // 98 for N=100000 (<=128)
  dim3 blk(256);

  // CSR build
  k_zero<<<dim3(256), blk, 0, stream>>>(cntcur, 2 * N);
  k_count<<<dim3((E + 255) / 256), blk, 0, stream>>>(e_dst, cnt, E);
  k_scan1<<<dim3(nb_scan), blk, 0, stream>>>(cnt, N, bsum);
  k_scan2<<<dim3(1), dim3(128), 0, stream>>>(bsum, nb_scan, offs + N);
  k_scan3<<<dim3(nb_scan), blk, 0, stream>>>(cnt, N, bsum, offs, dinv);
  k_scatter<<<dim3((E + 255) / 256), blk, 0, stream>>>(e_src, e_dst, dinv, offs, cur, csr, E);

  // layer 1 GEMM: 1 wave per 64 rows
  k_mm1<<<dim3((N + 63) / 64), dim3(64), 0, stream>>>(x_ids, emb, W1, bufA, N);
  // fused conv+next-GEMM chain (4 nodes/wave)
  k_agg<false><<<dim3(2048), blk, 0, stream>>>(bufA, csr, offs, dinv, b1, W2, bufB, N);
  k_agg<false><<<dim3(2048), blk, 0, stream>>>(bufB, csr, offs, dinv, b2, W3, bufA, N);
  k_agg<true><<<dim3(2048), blk, 0, stream>>>(bufA, csr, offs, dinv, b3, nullptr, bufB, N);

  // pool + MLP head
  k_pool<<<dim3(G), blk, 0, stream>>>(bufB, batch, N, Wf1, bf1, Wf2, bf2, out);
}